// Round 2
// baseline (353.363 us; speedup 1.0000x reference)
//
#include <hip/hip_runtime.h>
#include <hip/hip_cooperative_groups.h>
#include <math.h>

namespace cg = cooperative_groups;

// TopDownHTMM: C=32 states, 4-ary tree depth 7, N=21845 nodes, M=256 symbols.
// Single cooperative kernel: softmax precompute -> down(prior,beta) ->
// up(t_beta, beta) -> down(eps + fused likelihood) -> scalar reduce.
//
// parent(n) = (n-1)>>2, pos(n) = (n-1)&3, level offsets OFF[].

#define NNODES 21845
#define NF (NNODES * 32)
#define GBLK 128

enum : int {
  W_PRIOR = 0,             // [N][32]
  W_BETA  = NF,            // [N][32]
  W_TBETA = 2 * NF,        // [N][32]
  W_EPS   = 3 * NF,        // [N][32]
  W_SBT   = 4 * NF,        // smB^T [s][i]      (8192)
  W_LBT   = W_SBT + 8192,  // log smB^T [s][i]  (8192)
  W_PART  = W_LBT + 8192,  // per-block lh partials (GBLK)
};

__device__ inline float hsum32(float v) {
#pragma unroll
  for (int m = 16; m >= 1; m >>= 1) v += __shfl_xor(v, m, 32);
  return v;
}

// lane = i (output state). prior[n] = sum_j smA[i][j][e] * prior[pa][j]
__device__ inline void down_op(int n, int lane, const float* sAT,
                               float* __restrict__ W, const int* __restrict__ labels,
                               int leaf) {
  int pa = (n - 1) >> 2, e = (n - 1) & 3;
  float pj = W[W_PRIOR + pa * 32 + lane];
  float acc = 0.f;
#pragma unroll
  for (int j = 0; j < 32; j++)
    acc += sAT[e * 1024 + j * 32 + lane] * __shfl(pj, j, 32);
  W[W_PRIOR + n * 32 + lane] = acc;
  float bv = acc * W[W_SBT + labels[n] * 32 + lane];
  if (leaf) { float s = hsum32(bv); bv /= s; }
  W[W_BETA + n * 32 + lane] = bv;
}

// lane = j. One parent per 32-lane group: t_beta of 4 children + beta[pa] update.
__device__ inline void up_op(int pa, int j, const float* sA, float* __restrict__ W) {
  float ppj = W[W_PRIOR + pa * 32 + j];
  float prod = 1.f;
#pragma unroll
  for (int c = 0; c < 4; c++) {
    int n = 4 * pa + 1 + c;  // pos(n) == c
    float bc = W[W_BETA + n * 32 + j];
    float acc = 0.f;
#pragma unroll
    for (int i = 0; i < 32; i++)
      acc += sA[c * 1024 + i * 32 + j] * __shfl(bc, i, 32);
    float buv = acc / ppj;
    W[W_TBETA + n * 32 + j] = buv;
    prod *= buv;
  }
  float bnew = W[W_BETA + pa * 32 + j] * prod;
  float s = hsum32(bnew);
  bnew /= s;
  W[W_BETA + pa * 32 + j] = bnew;
  if (pa == 0) W[W_EPS + j] = bnew;  // eps[root] = beta[root]
}

// lane = i. eps + fused t_eps row-sum + A_lh + B_lh contribution (returned).
__device__ inline float eps_op(int n, int i, const float* sAT, const float* sLT,
                               float* __restrict__ W, const int* __restrict__ labels) {
  int pa = (n - 1) >> 2, e = (n - 1) & 3;
  float ratio = W[W_BETA + n * 32 + i] / W[W_PRIOR + n * 32 + i];
  float q = W[W_EPS + pa * 32 + i] / W[W_TBETA + n * 32 + i];  // q[j] held by lane j
  float num = 0.f, alh = 0.f;
#pragma unroll
  for (int j = 0; j < 32; j++) {
    float s = __shfl(q, j, 32);
    float te = ratio * sAT[e * 1024 + j * 32 + i] * s;  // t_eps[i][j]
    num += te;
    alh += te * sLT[e * 1024 + j * 32 + i];
  }
  float den = hsum32(num);
  float epsi = num / den;
  W[W_EPS + n * 32 + i] = epsi;
  return alh + epsi * W[W_LBT + labels[n] * 32 + i];
}

__global__ __launch_bounds__(256, 1) void k_all(const float* __restrict__ A,
                                                const float* __restrict__ Bm,
                                                const float* __restrict__ Pi,
                                                const int* __restrict__ labels,
                                                float* __restrict__ W,
                                                float* __restrict__ out) {
  __shared__ float sAT[4096];  // [e][j][i] = smA[i][j][e]
  __shared__ float sA[4096];   // [e][i][j] = smA[i][j][e]
  __shared__ float sLT[4096];  // [e][j][i] = log smA[i][j][e]
  __shared__ float sPi[32], sLpi[32];
  __shared__ float sred[4];

  const int OFF[9] = {0, 1, 5, 21, 85, 341, 1365, 5461, 21845};
  cg::grid_group grid = cg::this_grid();
  int tid = threadIdx.x;
  int bid = blockIdx.x;

  // ---- P0: softmaxes. A/Pi redundantly per block into LDS; B rows to global.
  if (tid < 128) {  // one (e,j) column of A, softmax over i; skewed i to avoid bank conflicts
    int e = tid >> 5, j = tid & 31;
    float m = -1e30f;
    for (int i = 0; i < 32; i++) m = fmaxf(m, A[(i * 32 + j) * 4 + e]);
    float s = 0.f;
    for (int i = 0; i < 32; i++) s += expf(A[(i * 32 + j) * 4 + e] - m);
    float ls = logf(s), inv = 1.f / s;
    for (int k = 0; k < 32; k++) {
      int i = (k + j) & 31;
      float a = A[(i * 32 + j) * 4 + e];
      float sm = expf(a - m) * inv;
      sAT[e * 1024 + j * 32 + i] = sm;
      sA [e * 1024 + i * 32 + j] = sm;
      sLT[e * 1024 + j * 32 + i] = (a - m) - ls;
    }
  } else if (tid == 128) {  // smPi
    float m = -1e30f;
    for (int i = 0; i < 32; i++) m = fmaxf(m, Pi[i]);
    float s = 0.f;
    for (int i = 0; i < 32; i++) s += expf(Pi[i] - m);
    float ls = logf(s);
    for (int i = 0; i < 32; i++) {
      sPi[i] = expf(Pi[i] - m) / s;
      sLpi[i] = (Pi[i] - m) - ls;
    }
  }
  // B softmax: one row per wave, blocks 0..7 (32 rows), 4 cols/lane.
  if (bid < 8) {
    int wave = tid >> 6, lane = tid & 63;
    int r = bid * 4 + wave;
    float x0 = Bm[r * 256 + lane],       x1 = Bm[r * 256 + 64 + lane];
    float x2 = Bm[r * 256 + 128 + lane], x3 = Bm[r * 256 + 192 + lane];
    float m = fmaxf(fmaxf(x0, x1), fmaxf(x2, x3));
#pragma unroll
    for (int o = 32; o >= 1; o >>= 1) m = fmaxf(m, __shfl_xor(m, o, 64));
    float e0 = expf(x0 - m), e1 = expf(x1 - m), e2 = expf(x2 - m), e3 = expf(x3 - m);
    float s = e0 + e1 + e2 + e3;
#pragma unroll
    for (int o = 32; o >= 1; o >>= 1) s += __shfl_xor(s, o, 64);
    float inv = 1.f / s, ls = logf(s);
    W[W_SBT + (lane      ) * 32 + r] = e0 * inv;
    W[W_SBT + (lane +  64) * 32 + r] = e1 * inv;
    W[W_SBT + (lane + 128) * 32 + r] = e2 * inv;
    W[W_SBT + (lane + 192) * 32 + r] = e3 * inv;
    W[W_LBT + (lane      ) * 32 + r] = (x0 - m) - ls;
    W[W_LBT + (lane +  64) * 32 + r] = (x1 - m) - ls;
    W[W_LBT + (lane + 128) * 32 + r] = (x2 - m) - ls;
    W[W_LBT + (lane + 192) * 32 + r] = (x3 - m) - ls;
  }
  __syncthreads();
  grid.sync();

  // ---- Down sweep: prior + beta.
  if (bid == 0) {
    if (tid < 32) {
      W[W_PRIOR + tid] = sPi[tid];
      W[W_BETA + tid] = sPi[tid] * W[W_SBT + labels[0] * 32 + tid];
    }
    for (int l = 1; l <= 4; l++) {  // 340 nodes total, block-local
      __syncthreads();
      int st = OFF[l], cnt = OFF[l + 1] - OFF[l];
      for (int base = 0; base < cnt; base += 8) {
        int idx = base + (tid >> 5);
        if (idx < cnt) down_op(st + idx, tid & 31, sAT, W, labels, 0);
      }
    }
  }
  grid.sync();
  for (int l = 5; l <= 7; l++) {
    int st = OFF[l], cnt = OFF[l + 1] - OFF[l];
    for (int base = bid * 8; base < cnt; base += GBLK * 8) {
      int idx = base + (tid >> 5);
      if (idx < cnt) down_op(st + idx, tid & 31, sAT, W, labels, l == 7);
    }
    grid.sync();
  }

  // ---- Up sweep: t_beta + beta updates. Child level l, parents at l-1.
  for (int l = 7; l >= 5; l--) {
    int pSt = OFF[l - 1], pcnt = OFF[l] - OFF[l - 1];
    for (int base = bid * 8; base < pcnt; base += GBLK * 8) {
      int idx = base + (tid >> 5);
      if (idx < pcnt) up_op(pSt + idx, tid & 31, sA, W);
    }
    grid.sync();
  }
  if (bid == 0) {
    for (int l = 4; l >= 1; l--) {  // 85 parents total, block-local
      int pSt = OFF[l - 1], pcnt = OFF[l] - OFF[l - 1];
      for (int base = 0; base < pcnt; base += 8) {
        int idx = base + (tid >> 5);
        if (idx < pcnt) up_op(pSt + idx, tid & 31, sA, W);
      }
      __syncthreads();
    }
  }
  grid.sync();

  // ---- Eps sweep + fused likelihood.
  float lh = 0.f;
  if (bid == 0) {
    for (int l = 1; l <= 3; l++) {  // 84 nodes, block-local
      __syncthreads();
      int st = OFF[l], cnt = OFF[l + 1] - OFF[l];
      for (int base = 0; base < cnt; base += 8) {
        int idx = base + (tid >> 5);
        if (idx < cnt) lh += eps_op(st + idx, tid & 31, sAT, sLT, W, labels);
      }
    }
  }
  grid.sync();
  for (int l = 4; l <= 7; l++) {
    int st = OFF[l], cnt = OFF[l + 1] - OFF[l];
    for (int base = bid * 8; base < cnt; base += GBLK * 8) {
      int idx = base + (tid >> 5);
      if (idx < cnt) lh += eps_op(st + idx, tid & 31, sAT, sLT, W, labels);
    }
    if (l < 7) grid.sync();
  }

  // ---- Reduce lh: block partial -> global -> block 0 final.
#pragma unroll
  for (int m = 32; m >= 1; m >>= 1) lh += __shfl_xor(lh, m, 64);
  if ((tid & 63) == 0) sred[tid >> 6] = lh;
  __syncthreads();
  if (tid == 0) W[W_PART + bid] = sred[0] + sred[1] + sred[2] + sred[3];
  grid.sync();
  if (bid == 0) {
    float a = (tid < GBLK) ? W[W_PART + tid] : 0.f;
    if (tid < 32) {
      float e0 = W[W_EPS + tid];
      a += e0 * (sLpi[tid] + W[W_LBT + labels[0] * 32 + tid]);  // Pi_lh + root B_lh
    }
#pragma unroll
    for (int m = 32; m >= 1; m >>= 1) a += __shfl_xor(a, m, 64);
    if ((tid & 63) == 0) sred[tid >> 6] = a;
    __syncthreads();
    if (tid == 0) out[0] = sred[0] + sred[1] + sred[2] + sred[3];
  }
}

extern "C" void kernel_launch(void* const* d_in, const int* in_sizes, int n_in,
                              void* d_out, int out_size, void* d_ws, size_t ws_size,
                              hipStream_t stream) {
  const float* A  = (const float*)d_in[0];
  const float* Bm = (const float*)d_in[1];
  const float* Pi = (const float*)d_in[2];
  const int* labels = (const int*)d_in[5];
  float* W = (float*)d_ws;
  float* out = (float*)d_out;

  void* args[] = {(void*)&A, (void*)&Bm, (void*)&Pi, (void*)&labels, (void*)&W, (void*)&out};
  hipLaunchCooperativeKernel((const void*)k_all, dim3(GBLK), dim3(256), args, 0u, stream);
}

// Round 3
// 97.592 us; speedup vs baseline: 3.6208x; 3.6208x over previous
//
#include <hip/hip_runtime.h>
#include <math.h>

// TopDownHTMM: C=32, 4-ary tree depth 7, N=21845, M=256. Output: scalar fp32.
// 6-kernel pipeline; levels 5-7 processed as 256 independent subtrees rooted
// at the 256 level-4 nodes (global node g of local node m in subtree r:
// g = 4^d * r + m, where d = local depth and m uses the same complete-tree
// arithmetic: parent=(m-1)>>2, pos=(m-1)&3).

#define NNODES 21845
#define NF (NNODES * 32)

enum : int {
  W_PRIOR = 0,             // [N][32]
  W_BETA  = NF,            // [N][32]
  W_TBETA = 2 * NF,        // [N][32]
  W_EPS   = 3 * NF,        // [N][32] (only nodes 0..84 used)
  W_AST   = 4 * NF,        // [e][j][i] = smA[i][j][e]      (4096)
  W_AS    = W_AST + 4096,  // [e][i][j] = smA[i][j][e]      (4096)
  W_ALT   = W_AS + 4096,   // [e][j][i] = log smA[i][j][e]  (4096)
  W_SPI   = W_ALT + 4096,  // smPi (32)
  W_LPI   = W_SPI + 32,    // log smPi (32)
  W_SBT   = W_LPI + 32,    // smB^T [s][i] (8192)
  W_LBT   = W_SBT + 8192,  // log smB^T [s][i] (8192)
  W_PART  = W_LBT + 8192,  // 257 lh partials
};

__device__ inline float hsum32(float v) {
#pragma unroll
  for (int m = 16; m >= 1; m >>= 1) v += __shfl_xor(v, m, 32);
  return v;
}

// ---------------- K1: softmax precompute (verbatim from round 1, verified) --
__global__ void k_precompute(const float* __restrict__ A, const float* __restrict__ Bm,
                             const float* __restrict__ Pi, float* __restrict__ W) {
  __shared__ float sh[256];
  int tid = threadIdx.x;
  int b = blockIdx.x;
  if (b < 32) {
    int r = b, s = tid;
    float x = Bm[r * 256 + s];
    sh[tid] = x; __syncthreads();
    for (int off = 128; off >= 1; off >>= 1) {
      if (tid < off) sh[tid] = fmaxf(sh[tid], sh[tid + off]);
      __syncthreads();
    }
    float m = sh[0]; __syncthreads();
    float e = expf(x - m);
    sh[tid] = e; __syncthreads();
    for (int off = 128; off >= 1; off >>= 1) {
      if (tid < off) sh[tid] += sh[tid + off];
      __syncthreads();
    }
    float sum = sh[0];
    W[W_SBT + s * 32 + r] = e / sum;
    W[W_LBT + s * 32 + r] = (x - m) - logf(sum);
  } else {
    if (tid < 128) {
      int e = tid >> 5, j = tid & 31;
      float m = -1e30f;
      for (int i = 0; i < 32; i++) m = fmaxf(m, A[(i * 32 + j) * 4 + e]);
      float s = 0.f;
      for (int i = 0; i < 32; i++) s += expf(A[(i * 32 + j) * 4 + e] - m);
      float ls = logf(s);
      for (int i = 0; i < 32; i++) {
        float a = A[(i * 32 + j) * 4 + e];
        float sm = expf(a - m) / s;
        W[W_AST + e * 1024 + j * 32 + i] = sm;
        W[W_AS  + e * 1024 + i * 32 + j] = sm;
        W[W_ALT + e * 1024 + j * 32 + i] = (a - m) - ls;
      }
    } else if (tid == 128) {
      float m = -1e30f;
      for (int i = 0; i < 32; i++) m = fmaxf(m, Pi[i]);
      float s = 0.f;
      for (int i = 0; i < 32; i++) s += expf(Pi[i] - m);
      float ls = logf(s);
      for (int i = 0; i < 32; i++) {
        W[W_SPI + i] = expf(Pi[i] - m) / s;
        W[W_LPI + i] = (Pi[i] - m) - ls;
      }
    }
  }
}

// ---------------- K2: root init + down levels 1..4 (one block, 1024 thr) ----
__global__ __launch_bounds__(1024) void k_down_small(const int* __restrict__ labels,
                                                     float* __restrict__ W) {
  __shared__ float sAT[4096];
  __shared__ float sp[85 * 32];   // prior, levels 0..3 (parents only)
  int tid = threadIdx.x;
  { float4* d4 = (float4*)sAT; const float4* g4 = (const float4*)(W + W_AST);
    d4[tid] = g4[tid]; }
  if (tid < 32) {
    float pr = W[W_SPI + tid];
    sp[tid] = pr;
    W[W_PRIOR + tid] = pr;
    W[W_BETA + tid] = pr * W[W_SBT + labels[0] * 32 + tid];
  }
  __syncthreads();
  const int OFF[6] = {0, 1, 5, 21, 85, 341};
  int grp = tid >> 5, lane = tid & 31;  // 32 groups
  for (int l = 1; l <= 4; l++) {
    int st = OFF[l], cnt = OFF[l + 1] - st;
    for (int base = 0; base < cnt; base += 32) {
      int idx = base + grp;
      if (idx < cnt) {
        int n = st + idx;
        int pa = (n - 1) >> 2, e = (n - 1) & 3;
        float acc = 0.f;
#pragma unroll
        for (int j = 0; j < 32; j++)
          acc += sAT[e * 1024 + j * 32 + lane] * sp[pa * 32 + j];
        if (n < 85) sp[n * 32 + lane] = acc;
        W[W_PRIOR + n * 32 + lane] = acc;
        W[W_BETA + n * 32 + lane] = acc * W[W_SBT + labels[n] * 32 + lane];
      }
    }
    __syncthreads();
  }
}

// ---------------- K3: per-subtree down 5-7 + up 7-5 (256 blocks) ------------
__global__ __launch_bounds__(256) void k_subtree(const int* __restrict__ labels,
                                                 float* __restrict__ W) {
  __shared__ float sAT[4096], sA[4096];
  __shared__ float sp[85 * 32], sb[85 * 32];
  int tid = threadIdx.x, bid = blockIdx.x;
  { float4* d4 = (float4*)sAT; const float4* g4 = (const float4*)(W + W_AST);
#pragma unroll
    for (int k = 0; k < 4; k++) d4[tid + 256 * k] = g4[tid + 256 * k];
    float4* d4b = (float4*)sA; const float4* g4b = (const float4*)(W + W_AS);
#pragma unroll
    for (int k = 0; k < 4; k++) d4b[tid + 256 * k] = g4b[tid + 256 * k]; }
  int grp = tid >> 5, lane = tid & 31;  // 8 groups
  const int r = 85 + bid;               // this block's level-4 root
  if (tid < 32) {
    sp[tid] = W[W_PRIOR + r * 32 + tid];
    sb[tid] = W[W_BETA + r * 32 + tid];
  }
  __syncthreads();
  const int LOFF[5] = {0, 1, 5, 21, 85};
  const int GPOW[4] = {1, 4, 16, 64};
  // down local levels 1..3 (global 5..7)
  for (int d = 1; d <= 3; d++) {
    int st = LOFF[d], cnt = LOFF[d + 1] - st;
    for (int base = 0; base < cnt; base += 8) {
      int idx = base + grp;
      if (idx < cnt) {
        int m = st + idx;
        int pa = (m - 1) >> 2, e = (m - 1) & 3;
        float acc = 0.f;
#pragma unroll
        for (int j = 0; j < 32; j++)
          acc += sAT[e * 1024 + j * 32 + lane] * sp[pa * 32 + j];
        sp[m * 32 + lane] = acc;
        int g = GPOW[d] * r + m;
        float bv = acc * W[W_SBT + labels[g] * 32 + lane];
        if (d == 3) { float s = hsum32(bv); bv /= s; }  // leaves
        sb[m * 32 + lane] = bv;
        W[W_PRIOR + g * 32 + lane] = acc;
      }
    }
    __syncthreads();
  }
  // up: parents at local levels 2,1,0 (t_beta of children -> global)
  for (int d = 2; d >= 0; d--) {
    int st = LOFF[d], cnt = LOFF[d + 1] - st;
    int gch = GPOW[d + 1] * r + LOFF[d + 1];
    for (int base = 0; base < cnt; base += 8) {
      int idx = base + grp;
      if (idx < cnt) {
        int p = st + idx;
        float ppj = sp[p * 32 + lane];
        float prod = 1.f;
#pragma unroll
        for (int c = 0; c < 4; c++) {
          int mch = 4 * p + 1 + c;
          float acc = 0.f;
#pragma unroll
          for (int i = 0; i < 32; i++)
            acc += sA[c * 1024 + i * 32 + lane] * sb[mch * 32 + i];
          float buv = acc / ppj;
          W[W_TBETA + (gch + 4 * idx + c) * 32 + lane] = buv;
          prod *= buv;
        }
        float bnew = sb[p * 32 + lane] * prod;
        float s = hsum32(bnew);
        sb[p * 32 + lane] = bnew / s;
      }
    }
    __syncthreads();
  }
  // write back final beta for local 0..84 (g = 4^d * r + m)
  for (int m = grp; m < 85; m += 8) {
    int d = (m == 0) ? 0 : (m < 5 ? 1 : (m < 21 ? 2 : 3));
    int g = GPOW[d] * r + m;
    W[W_BETA + g * 32 + lane] = sb[m * 32 + lane];
  }
}

// ---------------- K4: up levels 4..1 + eps levels 0..3 (one block, 1024) ----
__global__ __launch_bounds__(1024) void k_mid(const int* __restrict__ labels,
                                              float* __restrict__ W) {
  __shared__ float sA[4096];
  __shared__ float sb[85 * 32], stb[85 * 32], seps[85 * 32];
  __shared__ float sred[16];
  int tid = threadIdx.x;
  { float4* d4 = (float4*)sA; const float4* g4 = (const float4*)(W + W_AS);
    d4[tid] = g4[tid]; }
  for (int k = tid; k < 85 * 32; k += 1024) sb[k] = W[W_BETA + k];
  __syncthreads();
  int grp = tid >> 5, lane = tid & 31;  // 32 groups
  const int PST[4] = {21, 5, 1, 0}, PCNT[4] = {64, 16, 4, 1};
  for (int s = 0; s < 4; s++) {
    int st = PST[s], cnt = PCNT[s];
    for (int base = 0; base < cnt; base += 32) {
      int idx = base + grp;
      if (idx < cnt) {
        int p = st + idx;
        float ppj = W[W_PRIOR + p * 32 + lane];
        float prod = 1.f;
#pragma unroll
        for (int c = 0; c < 4; c++) {
          int n = 4 * p + 1 + c;
          float buv;
          if (s == 0) {  // children at level 4: beta from global (K3-final)
            float bc = W[W_BETA + n * 32 + lane];
            float acc = 0.f;
#pragma unroll
            for (int i = 0; i < 32; i++)
              acc += sA[c * 1024 + i * 32 + lane] * __shfl(bc, i, 32);
            buv = acc / ppj;
            W[W_TBETA + n * 32 + lane] = buv;      // needed by K5
          } else {
            float acc = 0.f;
#pragma unroll
            for (int i = 0; i < 32; i++)
              acc += sA[c * 1024 + i * 32 + lane] * sb[n * 32 + i];
            buv = acc / ppj;
            stb[n * 32 + lane] = buv;
          }
          prod *= buv;
        }
        float bnew = sb[p * 32 + lane] * prod;
        float ssum = hsum32(bnew);
        sb[p * 32 + lane] = bnew / ssum;
      }
    }
    __syncthreads();
  }
  if (tid < 32) {           // eps[root] = beta[root]
    float v = sb[tid];
    seps[tid] = v;
    W[W_EPS + tid] = v;
  }
  __syncthreads();
  float lh = 0.f;
  const int EST[3] = {1, 5, 21}, ECNT[3] = {4, 16, 64};
  for (int s = 0; s < 3; s++) {
    int st = EST[s], cnt = ECNT[s];
    for (int base = 0; base < cnt; base += 32) {
      int idx = base + grp;
      if (idx < cnt) {
        int n = st + idx;
        int pa = (n - 1) >> 2, e = (n - 1) & 3;
        float ratio = sb[n * 32 + lane] / W[W_PRIOR + n * 32 + lane];
        float qv = seps[pa * 32 + lane] / stb[n * 32 + lane];
        float num = 0.f, alh = 0.f;
#pragma unroll
        for (int j = 0; j < 32; j++) {
          float qq = __shfl(qv, j, 32);
          float a  = W[W_AST + e * 1024 + j * 32 + lane];  // L2-resident
          float la = W[W_ALT + e * 1024 + j * 32 + lane];
          float te = ratio * a * qq;
          num += te;
          alh += te * la;
        }
        float den = hsum32(num);
        float epsi = num / den;
        seps[n * 32 + lane] = epsi;
        W[W_EPS + n * 32 + lane] = epsi;                   // K5 needs levels<=3
        lh += alh + epsi * W[W_LBT + labels[n] * 32 + lane];
      }
    }
    __syncthreads();
  }
#pragma unroll
  for (int m = 32; m >= 1; m >>= 1) lh += __shfl_xor(lh, m, 64);
  if ((tid & 63) == 0) sred[tid >> 6] = lh;
  __syncthreads();
  if (tid == 0) {
    float t = 0.f;
#pragma unroll
    for (int w = 0; w < 16; w++) t += sred[w];
    W[W_PART + 256] = t;
  }
}

// ---------------- K5: per-subtree eps levels 4..7 + fused lh (256 blocks) ---
__global__ __launch_bounds__(256) void k_eps_sub(const int* __restrict__ labels,
                                                 float* __restrict__ W) {
  __shared__ float sAT[4096], sLT[4096];
  __shared__ float seps[85 * 32];
  __shared__ float sred[4];
  int tid = threadIdx.x, bid = blockIdx.x;
  { float4* d4 = (float4*)sAT; const float4* g4 = (const float4*)(W + W_AST);
#pragma unroll
    for (int k = 0; k < 4; k++) d4[tid + 256 * k] = g4[tid + 256 * k];
    float4* d4b = (float4*)sLT; const float4* g4b = (const float4*)(W + W_ALT);
#pragma unroll
    for (int k = 0; k < 4; k++) d4b[tid + 256 * k] = g4b[tid + 256 * k]; }
  int grp = tid >> 5, lane = tid & 31;
  const int r = 85 + bid;
  float lh = 0.f;
  __syncthreads();
  if (grp == 0) {  // eps at the level-4 root r
    int pa = (r - 1) >> 2, e = (r - 1) & 3;
    float ratio = W[W_BETA + r * 32 + lane] / W[W_PRIOR + r * 32 + lane];
    float qv = W[W_EPS + pa * 32 + lane] / W[W_TBETA + r * 32 + lane];
    float num = 0.f, alh = 0.f;
#pragma unroll
    for (int j = 0; j < 32; j++) {
      float qq = __shfl(qv, j, 32);
      float te = ratio * sAT[e * 1024 + j * 32 + lane] * qq;
      num += te;
      alh += te * sLT[e * 1024 + j * 32 + lane];
    }
    float den = hsum32(num);
    float epsi = num / den;
    seps[lane] = epsi;
    lh += alh + epsi * W[W_LBT + labels[r] * 32 + lane];
  }
  __syncthreads();
  const int LOFF[5] = {0, 1, 5, 21, 85};
  const int GPOW[4] = {1, 4, 16, 64};
  for (int d = 1; d <= 3; d++) {
    int st = LOFF[d], cnt = LOFF[d + 1] - st;
    for (int base = 0; base < cnt; base += 8) {
      int idx = base + grp;
      if (idx < cnt) {
        int m = st + idx;
        int pa = (m - 1) >> 2, e = (m - 1) & 3;
        int g = GPOW[d] * r + m;
        float ratio = W[W_BETA + g * 32 + lane] / W[W_PRIOR + g * 32 + lane];
        float qv = seps[pa * 32 + lane] / W[W_TBETA + g * 32 + lane];
        float num = 0.f, alh = 0.f;
#pragma unroll
        for (int j = 0; j < 32; j++) {
          float qq = __shfl(qv, j, 32);
          float te = ratio * sAT[e * 1024 + j * 32 + lane] * qq;
          num += te;
          alh += te * sLT[e * 1024 + j * 32 + lane];
        }
        float den = hsum32(num);
        float epsi = num / den;
        seps[m * 32 + lane] = epsi;
        lh += alh + epsi * W[W_LBT + labels[g] * 32 + lane];
      }
    }
    __syncthreads();
  }
#pragma unroll
  for (int m = 32; m >= 1; m >>= 1) lh += __shfl_xor(lh, m, 64);
  if ((tid & 63) == 0) sred[tid >> 6] = lh;
  __syncthreads();
  if (tid == 0) W[W_PART + bid] = sred[0] + sred[1] + sred[2] + sred[3];
}

// ---------------- K6: final reduce --------------------------------------
__global__ void k_final(const int* __restrict__ labels, const float* __restrict__ W,
                        float* __restrict__ out) {
  __shared__ float sh[512];
  int tid = threadIdx.x;
  float a = 0.f;
  for (int k = tid; k < 257; k += 512) a += W[W_PART + k];
  if (tid < 32) {
    float e0 = W[W_EPS + tid];
    a += e0 * (W[W_LPI + tid] + W[W_LBT + labels[0] * 32 + tid]);
  }
  sh[tid] = a; __syncthreads();
  for (int off = 256; off >= 1; off >>= 1) {
    if (tid < off) sh[tid] += sh[tid + off];
    __syncthreads();
  }
  if (tid == 0) out[0] = sh[0];
}

extern "C" void kernel_launch(void* const* d_in, const int* in_sizes, int n_in,
                              void* d_out, int out_size, void* d_ws, size_t ws_size,
                              hipStream_t stream) {
  const float* A  = (const float*)d_in[0];
  const float* Bm = (const float*)d_in[1];
  const float* Pi = (const float*)d_in[2];
  const int* labels = (const int*)d_in[5];
  float* W = (float*)d_ws;
  float* out = (float*)d_out;

  k_precompute<<<33, 256, 0, stream>>>(A, Bm, Pi, W);
  k_down_small<<<1, 1024, 0, stream>>>(labels, W);
  k_subtree<<<256, 256, 0, stream>>>(labels, W);
  k_mid<<<1, 1024, 0, stream>>>(labels, W);
  k_eps_sub<<<256, 256, 0, stream>>>(labels, W);
  k_final<<<1, 512, 0, stream>>>(labels, W, out);
}

// Round 4
// 74.049 us; speedup vs baseline: 4.7720x; 1.3179x over previous
//
#include <hip/hip_runtime.h>
#include <math.h>

// TopDownHTMM: C=32, 4-ary tree depth 7, N=21845, M=256. Output: scalar fp32.
// 6-kernel pipeline; levels 5-7 processed as 256 independent subtrees rooted
// at the 256 level-4 nodes. Global node g of local node m in subtree r:
// g = 4^d * r + m (d = local depth); parent=(m-1)>>2, pos=(m-1)&3 hold locally.
//
// v4: 1024-thread subtree kernels (4 waves/SIMD), ratio/t_beta-only global
// traffic for subtree nodes, all-LDS k_mid.

#define NNODES 21845
#define NF (NNODES * 32)

enum : int {
  W_PRIOR = 0,             // [N][32]  (rows 0..340 used)
  W_BETA  = NF,            // [N][32]  (rows 0..340 used)
  W_TBETA = 2 * NF,        // [N][32]  (rows 85..21844 used)
  W_RATIO = 3 * NF,        // [N][32]  (rows 85..21844 used: beta_final/prior)
  W_EPS   = 4 * NF,        // [N][32]  (rows 0..84 used)
  W_AST   = 5 * NF,        // [e][j][i] = smA[i][j][e]      (4096)
  W_AS    = W_AST + 4096,  // [e][i][j] = smA[i][j][e]      (4096)
  W_ALT   = W_AS + 4096,   // [e][j][i] = log smA[i][j][e]  (4096)
  W_SPI   = W_ALT + 4096,  // smPi (32)
  W_LPI   = W_SPI + 32,    // log smPi (32)
  W_SBT   = W_LPI + 32,    // smB^T [s][i] (8192)
  W_LBT   = W_SBT + 8192,  // log smB^T [s][i] (8192)
  W_PART  = W_LBT + 8192,  // 257 lh partials
};

__device__ inline float hsum32(float v) {
#pragma unroll
  for (int m = 16; m >= 1; m >>= 1) v += __shfl_xor(v, m, 32);
  return v;
}

// ---------------- K1: softmax precompute (verified round 1/3) ---------------
__global__ void k_precompute(const float* __restrict__ A, const float* __restrict__ Bm,
                             const float* __restrict__ Pi, float* __restrict__ W) {
  __shared__ float sh[256];
  int tid = threadIdx.x;
  int b = blockIdx.x;
  if (b < 32) {
    int r = b, s = tid;
    float x = Bm[r * 256 + s];
    sh[tid] = x; __syncthreads();
    for (int off = 128; off >= 1; off >>= 1) {
      if (tid < off) sh[tid] = fmaxf(sh[tid], sh[tid + off]);
      __syncthreads();
    }
    float m = sh[0]; __syncthreads();
    float e = expf(x - m);
    sh[tid] = e; __syncthreads();
    for (int off = 128; off >= 1; off >>= 1) {
      if (tid < off) sh[tid] += sh[tid + off];
      __syncthreads();
    }
    float sum = sh[0];
    W[W_SBT + s * 32 + r] = e / sum;
    W[W_LBT + s * 32 + r] = (x - m) - logf(sum);
  } else {
    if (tid < 128) {
      int e = tid >> 5, j = tid & 31;
      float m = -1e30f;
      for (int i = 0; i < 32; i++) m = fmaxf(m, A[(i * 32 + j) * 4 + e]);
      float s = 0.f;
      for (int i = 0; i < 32; i++) s += expf(A[(i * 32 + j) * 4 + e] - m);
      float ls = logf(s);
      for (int i = 0; i < 32; i++) {
        float a = A[(i * 32 + j) * 4 + e];
        float sm = expf(a - m) / s;
        W[W_AST + e * 1024 + j * 32 + i] = sm;
        W[W_AS  + e * 1024 + i * 32 + j] = sm;
        W[W_ALT + e * 1024 + j * 32 + i] = (a - m) - ls;
      }
    } else if (tid == 128) {
      float m = -1e30f;
      for (int i = 0; i < 32; i++) m = fmaxf(m, Pi[i]);
      float s = 0.f;
      for (int i = 0; i < 32; i++) s += expf(Pi[i] - m);
      float ls = logf(s);
      for (int i = 0; i < 32; i++) {
        W[W_SPI + i] = expf(Pi[i] - m) / s;
        W[W_LPI + i] = (Pi[i] - m) - ls;
      }
    }
  }
}

// ---------------- K2: root init + down levels 1..4 (one block, 1024 thr) ----
__global__ __launch_bounds__(1024) void k_down_small(const int* __restrict__ labels,
                                                     float* __restrict__ W) {
  __shared__ float sAT[4096];
  __shared__ float sp[85 * 32];
  int tid = threadIdx.x;
  { float4* d4 = (float4*)sAT; const float4* g4 = (const float4*)(W + W_AST);
    d4[tid] = g4[tid]; }
  if (tid < 32) {
    float pr = W[W_SPI + tid];
    sp[tid] = pr;
    W[W_PRIOR + tid] = pr;
    W[W_BETA + tid] = pr * W[W_SBT + labels[0] * 32 + tid];
  }
  __syncthreads();
  const int OFF[6] = {0, 1, 5, 21, 85, 341};
  int grp = tid >> 5, lane = tid & 31;
  for (int l = 1; l <= 4; l++) {
    int st = OFF[l], cnt = OFF[l + 1] - st;
    for (int base = 0; base < cnt; base += 32) {
      int idx = base + grp;
      if (idx < cnt) {
        int n = st + idx;
        int pa = (n - 1) >> 2, e = (n - 1) & 3;
        float acc = 0.f;
#pragma unroll
        for (int j = 0; j < 32; j++)
          acc += sAT[e * 1024 + j * 32 + lane] * sp[pa * 32 + j];
        if (n < 85) sp[n * 32 + lane] = acc;
        W[W_PRIOR + n * 32 + lane] = acc;
        W[W_BETA + n * 32 + lane] = acc * W[W_SBT + labels[n] * 32 + lane];
      }
    }
    __syncthreads();
  }
}

// ---------------- K3: per-subtree down 5-7 + up 7-5 (256 x 1024) ------------
__global__ __launch_bounds__(1024) void k_subtree(const int* __restrict__ labels,
                                                  float* __restrict__ W) {
  __shared__ float sAT[4096], sA[4096];
  __shared__ float sp[85 * 32], sb[85 * 32], sp3[32];
  int tid = threadIdx.x, bid = blockIdx.x;
  { float4* d4 = (float4*)sAT; const float4* g4 = (const float4*)(W + W_AST);
    d4[tid] = g4[tid];
    float4* d4b = (float4*)sA; const float4* g4b = (const float4*)(W + W_AS);
    d4b[tid] = g4b[tid]; }
  const int r = 85 + bid;
  const int pa_r = (r - 1) >> 2;
  if (tid < 32) {
    sp[tid] = W[W_PRIOR + r * 32 + tid];
    sb[tid] = W[W_BETA + r * 32 + tid];
  } else if (tid < 64) {
    sp3[tid - 32] = W[W_PRIOR + pa_r * 32 + (tid - 32)];
  }
  __syncthreads();
  int grp = tid >> 5, lane = tid & 31;  // 32 groups
  const int LOFF[5] = {0, 1, 5, 21, 85};
  const int GPOW[4] = {1, 4, 16, 64};
  // down local levels 1..3 (global 5..7)
  for (int d = 1; d <= 3; d++) {
    int st = LOFF[d], cnt = LOFF[d + 1] - st;
    for (int base = 0; base < cnt; base += 32) {
      int idx = base + grp;
      if (idx < cnt) {
        int m = st + idx;
        int pam = (m - 1) >> 2, e = (m - 1) & 3;
        float acc = 0.f;
#pragma unroll
        for (int j = 0; j < 32; j++)
          acc += sAT[e * 1024 + j * 32 + lane] * sp[pam * 32 + j];
        sp[m * 32 + lane] = acc;
        int g = GPOW[d] * r + m;
        float bv = acc * W[W_SBT + labels[g] * 32 + lane];
        if (d == 3) { float s = hsum32(bv); bv /= s; }  // leaves
        sb[m * 32 + lane] = bv;
      }
    }
    __syncthreads();
  }
  // up: parents at local levels 2,1,0
  for (int d = 2; d >= 0; d--) {
    int st = LOFF[d], cnt = LOFF[d + 1] - st;
    for (int base = 0; base < cnt; base += 32) {
      int idx = base + grp;
      if (idx < cnt) {
        int p = st + idx;
        float ppj = sp[p * 32 + lane];
        float prod = 1.f;
#pragma unroll
        for (int c = 0; c < 4; c++) {
          int mch = 4 * p + 1 + c;
          float acc = 0.f;
#pragma unroll
          for (int i = 0; i < 32; i++)
            acc += sA[c * 1024 + i * 32 + lane] * sb[mch * 32 + i];
          float buv = acc / ppj;
          int gch = GPOW[d + 1] * r + mch;
          W[W_TBETA + gch * 32 + lane] = buv;
          prod *= buv;
        }
        float bnew = sb[p * 32 + lane] * prod;
        float s = hsum32(bnew);
        sb[p * 32 + lane] = bnew / s;
      }
    }
    __syncthreads();
  }
  // t_beta for r itself (k_mid consumes) + ratio writeback for all local nodes
  if (tid < 32) {
    int e = (r - 1) & 3;
    float acc = 0.f;
#pragma unroll
    for (int i = 0; i < 32; i++) acc += sA[e * 1024 + i * 32 + lane] * sb[i];
    W[W_TBETA + r * 32 + lane] = acc / sp3[lane];
  }
  for (int m = grp; m < 85; m += 32) {
    int d = (m == 0) ? 0 : (m < 5 ? 1 : (m < 21 ? 2 : 3));
    int g = GPOW[d] * r + m;
    W[W_RATIO + g * 32 + lane] = sb[m * 32 + lane] / sp[m * 32 + lane];
  }
}

// ---------------- K4: up levels 4..1 + eps levels 0..3 (one block, 1024) ----
__global__ __launch_bounds__(1024) void k_mid(const int* __restrict__ labels,
                                              float* __restrict__ W) {
  __shared__ float sA[4096];
  __shared__ float sp[85 * 32], sb[85 * 32], stb[85 * 32], seps[85 * 32];
  __shared__ float sred[16];
  int tid = threadIdx.x;
  { float4* d4 = (float4*)sA; const float4* g4 = (const float4*)(W + W_AS);
    d4[tid] = g4[tid]; }
  for (int k = tid; k < 85 * 32; k += 1024) { sp[k] = W[W_PRIOR + k]; sb[k] = W[W_BETA + k]; }
  __syncthreads();
  int grp = tid >> 5, lane = tid & 31;  // 32 groups
  const int PST[4] = {21, 5, 1, 0}, PCNT[4] = {64, 16, 4, 1};
  for (int s = 0; s < 4; s++) {
    int st = PST[s], cnt = PCNT[s];
    for (int base = 0; base < cnt; base += 32) {
      int idx = base + grp;
      if (idx < cnt) {
        int p = st + idx;
        float prod = 1.f;
#pragma unroll
        for (int c = 0; c < 4; c++) {
          int n = 4 * p + 1 + c;
          float buv;
          if (s == 0) {
            buv = W[W_TBETA + n * 32 + lane];  // level-4 t_beta from K3
          } else {
            float acc = 0.f;
#pragma unroll
            for (int i = 0; i < 32; i++)
              acc += sA[c * 1024 + i * 32 + lane] * sb[n * 32 + i];
            buv = acc / sp[p * 32 + lane];
            stb[n * 32 + lane] = buv;
          }
          prod *= buv;
        }
        float bnew = sb[p * 32 + lane] * prod;
        float ssum = hsum32(bnew);
        sb[p * 32 + lane] = bnew / ssum;
      }
    }
    __syncthreads();
  }
  if (tid < 32) {  // eps[root] = beta[root]
    float v = sb[tid];
    seps[tid] = v;
    W[W_EPS + tid] = v;
  }
  __syncthreads();
  float lh = 0.f;
  const int EST[3] = {1, 5, 21}, ECNT[3] = {4, 16, 64};
  for (int s = 0; s < 3; s++) {
    int st = EST[s], cnt = ECNT[s];
    for (int base = 0; base < cnt; base += 32) {
      int idx = base + grp;
      if (idx < cnt) {
        int n = st + idx;
        int pa = (n - 1) >> 2, e = (n - 1) & 3;
        float ratio = sb[n * 32 + lane] / sp[n * 32 + lane];
        float qv = seps[pa * 32 + lane] / stb[n * 32 + lane];
        float num = 0.f, alh = 0.f;
#pragma unroll
        for (int j = 0; j < 32; j++) {
          float qq = __shfl(qv, j, 32);
          float a  = W[W_AST + e * 1024 + j * 32 + lane];
          float la = W[W_ALT + e * 1024 + j * 32 + lane];
          float te = ratio * a * qq;
          num += te;
          alh += te * la;
        }
        float den = hsum32(num);
        float epsi = num / den;
        seps[n * 32 + lane] = epsi;
        W[W_EPS + n * 32 + lane] = epsi;
        lh += alh + epsi * W[W_LBT + labels[n] * 32 + lane];
      }
    }
    __syncthreads();
  }
#pragma unroll
  for (int m = 32; m >= 1; m >>= 1) lh += __shfl_xor(lh, m, 64);
  if ((tid & 63) == 0) sred[tid >> 6] = lh;
  __syncthreads();
  if (tid == 0) {
    float t = 0.f;
#pragma unroll
    for (int w = 0; w < 16; w++) t += sred[w];
    W[W_PART + 256] = t;
  }
}

// ---------------- K5: per-subtree eps levels 4..7 + fused lh (256 x 1024) ---
__global__ __launch_bounds__(1024) void k_eps_sub(const int* __restrict__ labels,
                                                  float* __restrict__ W) {
  __shared__ float sAT[4096], sLT[4096];
  __shared__ float seps[85 * 32];
  __shared__ float sred[16];
  int tid = threadIdx.x, bid = blockIdx.x;
  { float4* d4 = (float4*)sAT; const float4* g4 = (const float4*)(W + W_AST);
    d4[tid] = g4[tid];
    float4* d4b = (float4*)sLT; const float4* g4b = (const float4*)(W + W_ALT);
    d4b[tid] = g4b[tid]; }
  int grp = tid >> 5, lane = tid & 31;  // 32 groups
  const int r = 85 + bid;
  float lh = 0.f;
  __syncthreads();
  if (grp == 0) {  // eps at the level-4 root r
    int pa = (r - 1) >> 2, e = (r - 1) & 3;
    float ratio = W[W_RATIO + r * 32 + lane];
    float qv = W[W_EPS + pa * 32 + lane] / W[W_TBETA + r * 32 + lane];
    float num = 0.f, alh = 0.f;
#pragma unroll
    for (int j = 0; j < 32; j++) {
      float qq = __shfl(qv, j, 32);
      float te = ratio * sAT[e * 1024 + j * 32 + lane] * qq;
      num += te;
      alh += te * sLT[e * 1024 + j * 32 + lane];
    }
    float den = hsum32(num);
    float epsi = num / den;
    seps[lane] = epsi;
    lh += alh + epsi * W[W_LBT + labels[r] * 32 + lane];
  }
  __syncthreads();
  const int LOFF[5] = {0, 1, 5, 21, 85};
  const int GPOW[4] = {1, 4, 16, 64};
  for (int d = 1; d <= 3; d++) {
    int st = LOFF[d], cnt = LOFF[d + 1] - st;
    for (int base = 0; base < cnt; base += 32) {
      int idx = base + grp;
      if (idx < cnt) {
        int m = st + idx;
        int pa = (m - 1) >> 2, e = (m - 1) & 3;
        int g = GPOW[d] * r + m;
        float ratio = W[W_RATIO + g * 32 + lane];
        float qv = seps[pa * 32 + lane] / W[W_TBETA + g * 32 + lane];
        float num = 0.f, alh = 0.f;
#pragma unroll
        for (int j = 0; j < 32; j++) {
          float qq = __shfl(qv, j, 32);
          float te = ratio * sAT[e * 1024 + j * 32 + lane] * qq;
          num += te;
          alh += te * sLT[e * 1024 + j * 32 + lane];
        }
        float den = hsum32(num);
        float epsi = num / den;
        seps[m * 32 + lane] = epsi;
        lh += alh + epsi * W[W_LBT + labels[g] * 32 + lane];
      }
    }
    __syncthreads();
  }
#pragma unroll
  for (int m = 32; m >= 1; m >>= 1) lh += __shfl_xor(lh, m, 64);
  if ((tid & 63) == 0) sred[tid >> 6] = lh;
  __syncthreads();
  if (tid == 0) {
    float t = 0.f;
#pragma unroll
    for (int w = 0; w < 16; w++) t += sred[w];
    W[W_PART + bid] = t;
  }
}

// ---------------- K6: final reduce ------------------------------------------
__global__ void k_final(const int* __restrict__ labels, const float* __restrict__ W,
                        float* __restrict__ out) {
  __shared__ float sh[512];
  int tid = threadIdx.x;
  float a = 0.f;
  for (int k = tid; k < 257; k += 512) a += W[W_PART + k];
  if (tid < 32) {
    float e0 = W[W_EPS + tid];
    a += e0 * (W[W_LPI + tid] + W[W_LBT + labels[0] * 32 + tid]);
  }
  sh[tid] = a; __syncthreads();
  for (int off = 256; off >= 1; off >>= 1) {
    if (tid < off) sh[tid] += sh[tid + off];
    __syncthreads();
  }
  if (tid == 0) out[0] = sh[0];
}

extern "C" void kernel_launch(void* const* d_in, const int* in_sizes, int n_in,
                              void* d_out, int out_size, void* d_ws, size_t ws_size,
                              hipStream_t stream) {
  const float* A  = (const float*)d_in[0];
  const float* Bm = (const float*)d_in[1];
  const float* Pi = (const float*)d_in[2];
  const int* labels = (const int*)d_in[5];
  float* W = (float*)d_ws;
  float* out = (float*)d_out;

  k_precompute<<<33, 256, 0, stream>>>(A, Bm, Pi, W);
  k_down_small<<<1, 1024, 0, stream>>>(labels, W);
  k_subtree<<<256, 1024, 0, stream>>>(labels, W);
  k_mid<<<1, 1024, 0, stream>>>(labels, W);
  k_eps_sub<<<256, 1024, 0, stream>>>(labels, W);
  k_final<<<1, 512, 0, stream>>>(labels, W, out);
}

// Round 5
// 65.733 us; speedup vs baseline: 5.3758x; 1.1265x over previous
//
#include <hip/hip_runtime.h>
#include <math.h>

// TopDownHTMM: C=32, 4-ary tree depth 7, N=21845, M=256. Output: scalar fp32.
// 4-kernel pipeline: k_pre (softmaxes) -> k_sub (256 subtrees: path + down 5-7
// + up 7-5) -> k_mid (down 0-3, up 4-1, eps 0-3) -> k_eps_sub (eps 4-7).
// Likelihood accumulated via atomicAdd into out[0] (zeroed by k_pre).
//
// Subtree r in [85,341): local node m in [0,85), local depth d, global id
// g = 4^d * r + m; parent=(m-1)>>2, pos=(m-1)&3 hold locally.

#define NNODES 21845
#define NF (NNODES * 32)

enum : int {
  W_TBETA = 0,             // [N][32] rows 85..21844
  W_RATIO = NF,            // [N][32] rows 85..21844 (beta_final/prior)
  W_EPS   = 2 * NF,        // rows 0..84 used
  W_AST   = 2 * NF + 85 * 32,  // [e][j][i] = smA[i][j][e]      (4096)
  W_AS    = W_AST + 4096,  // [e][i][j] = smA[i][j][e]          (4096)
  W_ALT   = W_AS + 4096,   // [e][j][i] = log smA[i][j][e]      (4096)
  W_SPI   = W_ALT + 4096,  // smPi (32)
  W_LPI   = W_SPI + 32,    // log smPi (32)
  W_SBT   = W_LPI + 32,    // smB^T [s][i] (8192)
  W_LBT   = W_SBT + 8192,  // log smB^T [s][i] (8192)
};

__device__ inline float hsum32(float v) {
#pragma unroll
  for (int m = 16; m >= 1; m >>= 1) v += __shfl_xor(v, m, 32);
  return v;
}

// ---------------- K1: softmax precompute + out zero -------------------------
__global__ void k_pre(const float* __restrict__ A, const float* __restrict__ Bm,
                      const float* __restrict__ Pi, float* __restrict__ W,
                      float* __restrict__ out) {
  __shared__ float sh[256];
  int tid = threadIdx.x;
  int b = blockIdx.x;
  if (b < 32) {
    int r = b, s = tid;
    float x = Bm[r * 256 + s];
    sh[tid] = x; __syncthreads();
    for (int off = 128; off >= 1; off >>= 1) {
      if (tid < off) sh[tid] = fmaxf(sh[tid], sh[tid + off]);
      __syncthreads();
    }
    float m = sh[0]; __syncthreads();
    float e = expf(x - m);
    sh[tid] = e; __syncthreads();
    for (int off = 128; off >= 1; off >>= 1) {
      if (tid < off) sh[tid] += sh[tid + off];
      __syncthreads();
    }
    float sum = sh[0];
    W[W_SBT + s * 32 + r] = e / sum;
    W[W_LBT + s * 32 + r] = (x - m) - logf(sum);
  } else {
    if (tid < 128) {
      int e = tid >> 5, j = tid & 31;
      float m = -1e30f;
      for (int i = 0; i < 32; i++) m = fmaxf(m, A[(i * 32 + j) * 4 + e]);
      float s = 0.f;
      for (int i = 0; i < 32; i++) s += expf(A[(i * 32 + j) * 4 + e] - m);
      float ls = logf(s);
      for (int i = 0; i < 32; i++) {
        float a = A[(i * 32 + j) * 4 + e];
        float sm = expf(a - m) / s;
        W[W_AST + e * 1024 + j * 32 + i] = sm;
        W[W_AS  + e * 1024 + i * 32 + j] = sm;
        W[W_ALT + e * 1024 + j * 32 + i] = (a - m) - ls;
      }
    } else if (tid == 128) {
      float m = -1e30f;
      for (int i = 0; i < 32; i++) m = fmaxf(m, Pi[i]);
      float s = 0.f;
      for (int i = 0; i < 32; i++) s += expf(Pi[i] - m);
      float ls = logf(s);
      for (int i = 0; i < 32; i++) {
        W[W_SPI + i] = expf(Pi[i] - m) / s;
        W[W_LPI + i] = (Pi[i] - m) - ls;
      }
    } else if (tid == 129) {
      out[0] = 0.f;
    }
  }
}

// global row index for local node m of subtree r
__device__ inline int gmap(int r, int m) {
  return (m == 0) ? r : (m < 5 ? 4 * r + m : (m < 21 ? 16 * r + m : 64 * r + m));
}

// ---------------- K2: per-subtree path + down 5-7 + up 7-5 (256 x 1024) -----
__global__ __launch_bounds__(1024) void k_sub(const int* __restrict__ labels,
                                              float* __restrict__ W) {
  __shared__ float sAT[4096], sA[4096];
  __shared__ float sp[85 * 32], sb[85 * 32], stb[85 * 32];
  __shared__ float spath[32], sp3[32];
  int tid = threadIdx.x, bid = blockIdx.x;
  { float4* d4 = (float4*)sAT; const float4* g4 = (const float4*)(W + W_AST);
    d4[tid] = g4[tid];
    float4* d4b = (float4*)sA; const float4* g4b = (const float4*)(W + W_AS);
    d4b[tid] = g4b[tid]; }
  const int r = 85 + bid;
  const int a3 = (r - 1) >> 2, a2 = (a3 - 1) >> 2, a1 = (a2 - 1) >> 2;
  if (tid < 32) spath[tid] = W[W_SPI + tid];
  __syncthreads();
  // path: prior chain root -> a1 -> a2 -> a3 -> r
  int anc[4] = {a1, a2, a3, r};
  float accp = 0.f;
#pragma unroll
  for (int s = 0; s < 4; s++) {
    if (tid < 32) {
      int e = (anc[s] - 1) & 3;
      accp = 0.f;
#pragma unroll
      for (int j = 0; j < 32; j++)
        accp += sAT[e * 1024 + j * 32 + tid] * spath[j];
    }
    __syncthreads();
    if (tid < 32) {
      spath[tid] = accp;
      if (s == 2) sp3[tid] = accp;  // prior at parent(r)
    }
    __syncthreads();
  }
  if (tid < 32) {
    sp[tid] = spath[tid];
    sb[tid] = spath[tid] * W[W_SBT + labels[r] * 32 + tid];
  }
  __syncthreads();
  int grp = tid >> 5, lane = tid & 31;  // 32 groups
  const int LOFF[5] = {0, 1, 5, 21, 85};
  const int GPOW[4] = {1, 4, 16, 64};
  // down local levels 1..3 (global 5..7)
  for (int d = 1; d <= 3; d++) {
    int st = LOFF[d], cnt = LOFF[d + 1] - st;
    for (int base = 0; base < cnt; base += 32) {
      int idx = base + grp;
      if (idx < cnt) {
        int m = st + idx;
        int pam = (m - 1) >> 2, e = (m - 1) & 3;
        float acc = 0.f;
#pragma unroll
        for (int j = 0; j < 32; j++)
          acc += sAT[e * 1024 + j * 32 + lane] * sp[pam * 32 + j];
        sp[m * 32 + lane] = acc;
        int g = GPOW[d] * r + m;
        float bv = acc * W[W_SBT + labels[g] * 32 + lane];
        if (d == 3) { float s = hsum32(bv); bv /= s; }  // leaves normalized
        sb[m * 32 + lane] = bv;
      }
    }
    __syncthreads();
  }
  // up: parents at local levels 2,1,0; t_beta staged in LDS
  for (int d = 2; d >= 0; d--) {
    int st = LOFF[d], cnt = LOFF[d + 1] - st;
    for (int base = 0; base < cnt; base += 32) {
      int idx = base + grp;
      if (idx < cnt) {
        int p = st + idx;
        float ppj = sp[p * 32 + lane];
        float prod = 1.f;
#pragma unroll
        for (int c = 0; c < 4; c++) {
          int mch = 4 * p + 1 + c;
          float acc = 0.f;
#pragma unroll
          for (int i = 0; i < 32; i++)
            acc += sA[c * 1024 + i * 32 + lane] * sb[mch * 32 + i];
          float buv = acc / ppj;
          stb[mch * 32 + lane] = buv;
          prod *= buv;
        }
        float bnew = sb[p * 32 + lane] * prod;
        float s = hsum32(bnew);
        sb[p * 32 + lane] = bnew / s;
      }
    }
    __syncthreads();
  }
  // t_beta for r itself (uses FINAL local-root beta and prior[parent(r)])
  if (tid < 32) {
    int e = (r - 1) & 3;
    float acc = 0.f;
#pragma unroll
    for (int i = 0; i < 32; i++) acc += sA[e * 1024 + i * 32 + tid] * sb[i];
    stb[tid] = acc / sp3[tid];
  }
  __syncthreads();
  // coalesced float4 writeback: t_beta + ratio for all 85 local rows
  if (tid < 680) {
    int m = tid >> 3, q = tid & 7;
    int g = gmap(r, m);
    float4 tb = *(float4*)&stb[m * 32 + q * 4];
    *(float4*)&W[W_TBETA + g * 32 + q * 4] = tb;
    float4 bb = *(float4*)&sb[m * 32 + q * 4];
    float4 pp = *(float4*)&sp[m * 32 + q * 4];
    float4 rr;
    rr.x = bb.x / pp.x; rr.y = bb.y / pp.y; rr.z = bb.z / pp.z; rr.w = bb.w / pp.w;
    *(float4*)&W[W_RATIO + g * 32 + q * 4] = rr;
  }
}

// ---------------- K3: down 0-3, up 4-1, eps 0-3, partial lh (1 x 1024) ------
__global__ __launch_bounds__(1024) void k_mid(const int* __restrict__ labels,
                                              float* __restrict__ W,
                                              float* __restrict__ out) {
  __shared__ float sA[4096], sAT[4096], sLT[4096];
  __shared__ float stb4[256 * 32];   // level-4 t_beta (rows 85..340)
  __shared__ float sp[85 * 32], sb[85 * 32], stb[85 * 32], seps[85 * 32];
  __shared__ float sred[16];
  int tid = threadIdx.x;
  { float4* d4 = (float4*)sA;  const float4* g4 = (const float4*)(W + W_AS);
    d4[tid] = g4[tid];
    float4* d5 = (float4*)sAT; const float4* g5 = (const float4*)(W + W_AST);
    d5[tid] = g5[tid];
    float4* d6 = (float4*)sLT; const float4* g6 = (const float4*)(W + W_ALT);
    d6[tid] = g6[tid];
    float4* d7 = (float4*)stb4; const float4* g7 = (const float4*)(W + W_TBETA + 85 * 32);
    d7[tid] = g7[tid]; d7[tid + 1024] = g7[tid + 1024]; }
  int grp = tid >> 5, lane = tid & 31;  // 32 groups
  if (tid < 32) {
    float pr = W[W_SPI + tid];
    sp[tid] = pr;
    sb[tid] = pr * W[W_SBT + labels[0] * 32 + tid];
  }
  __syncthreads();
  const int OFF[5] = {0, 1, 5, 21, 85};
  // down levels 1..3
  for (int l = 1; l <= 3; l++) {
    int st = OFF[l], cnt = OFF[l + 1] - st;
    for (int base = 0; base < cnt; base += 32) {
      int idx = base + grp;
      if (idx < cnt) {
        int n = st + idx;
        int pa = (n - 1) >> 2, e = (n - 1) & 3;
        float acc = 0.f;
#pragma unroll
        for (int j = 0; j < 32; j++)
          acc += sAT[e * 1024 + j * 32 + lane] * sp[pa * 32 + j];
        sp[n * 32 + lane] = acc;
        sb[n * 32 + lane] = acc * W[W_SBT + labels[n] * 32 + lane];
      }
    }
    __syncthreads();
  }
  // up stages: parents level 3,2,1,0
  const int PST[4] = {21, 5, 1, 0}, PCNT[4] = {64, 16, 4, 1};
  for (int s = 0; s < 4; s++) {
    int st = PST[s], cnt = PCNT[s];
    for (int base = 0; base < cnt; base += 32) {
      int idx = base + grp;
      if (idx < cnt) {
        int p = st + idx;
        float prod = 1.f;
#pragma unroll
        for (int c = 0; c < 4; c++) {
          int n = 4 * p + 1 + c;
          float buv;
          if (s == 0) {
            buv = stb4[(n - 85) * 32 + lane];  // level-4 t_beta from K2
          } else {
            float acc = 0.f;
#pragma unroll
            for (int i = 0; i < 32; i++)
              acc += sA[c * 1024 + i * 32 + lane] * sb[n * 32 + i];
            buv = acc / sp[p * 32 + lane];
            stb[n * 32 + lane] = buv;
          }
          prod *= buv;
        }
        float bnew = sb[p * 32 + lane] * prod;
        float ssum = hsum32(bnew);
        sb[p * 32 + lane] = bnew / ssum;
      }
    }
    __syncthreads();
  }
  float lh = 0.f;
  if (tid < 32) {  // eps[root] = beta[root]; root Pi + B terms
    float v = sb[tid];
    seps[tid] = v;
    lh += v * (W[W_LPI + tid] + W[W_LBT + labels[0] * 32 + tid]);
  }
  __syncthreads();
  const int EST[3] = {1, 5, 21}, ECNT[3] = {4, 16, 64};
  for (int s = 0; s < 3; s++) {
    int st = EST[s], cnt = ECNT[s];
    for (int base = 0; base < cnt; base += 32) {
      int idx = base + grp;
      if (idx < cnt) {
        int n = st + idx;
        int pa = (n - 1) >> 2, e = (n - 1) & 3;
        float ratio = sb[n * 32 + lane] / sp[n * 32 + lane];
        float qv = seps[pa * 32 + lane] / stb[n * 32 + lane];
        float num = 0.f, alh = 0.f;
#pragma unroll
        for (int j = 0; j < 32; j++) {
          float qq = __shfl(qv, j, 32);
          float te = ratio * sAT[e * 1024 + j * 32 + lane] * qq;
          num += te;
          alh += te * sLT[e * 1024 + j * 32 + lane];
        }
        float den = hsum32(num);
        float epsi = num / den;
        seps[n * 32 + lane] = epsi;
        lh += alh + epsi * W[W_LBT + labels[n] * 32 + lane];
      }
    }
    __syncthreads();
  }
  // write eps rows 0..84 coalesced (k_eps_sub reads parent rows at level 3)
  if (tid < 680) {
    int m = tid >> 3, q = tid & 7;
    *(float4*)&W[W_EPS + m * 32 + q * 4] = *(float4*)&seps[m * 32 + q * 4];
  }
#pragma unroll
  for (int m = 32; m >= 1; m >>= 1) lh += __shfl_xor(lh, m, 64);
  if ((tid & 63) == 0) sred[tid >> 6] = lh;
  __syncthreads();
  if (tid == 0) {
    float t = 0.f;
#pragma unroll
    for (int w = 0; w < 16; w++) t += sred[w];
    atomicAdd(out, t);
  }
}

// ---------------- K4: per-subtree eps 4-7 + fused lh (256 x 1024) -----------
__global__ __launch_bounds__(1024) void k_eps_sub(const int* __restrict__ labels,
                                                  float* __restrict__ W,
                                                  float* __restrict__ out) {
  __shared__ float sAT[4096], sLT[4096];
  __shared__ float stb[85 * 32], srt[85 * 32], seps[85 * 32];
  __shared__ float spe[32];
  __shared__ float sred[16];
  int tid = threadIdx.x, bid = blockIdx.x;
  const int r = 85 + bid;
  { float4* d4 = (float4*)sAT; const float4* g4 = (const float4*)(W + W_AST);
    d4[tid] = g4[tid];
    float4* d4b = (float4*)sLT; const float4* g4b = (const float4*)(W + W_ALT);
    d4b[tid] = g4b[tid]; }
  // prefetch t_beta + ratio rows for all 85 local nodes (coalesced float4)
  if (tid < 680) {
    int m = tid >> 3, q = tid & 7;
    int g = gmap(r, m);
    *(float4*)&stb[m * 32 + q * 4] = *(const float4*)&W[W_TBETA + g * 32 + q * 4];
    *(float4*)&srt[m * 32 + q * 4] = *(const float4*)&W[W_RATIO + g * 32 + q * 4];
  }
  if (tid >= 992) spe[tid - 992] = W[W_EPS + ((r - 1) >> 2) * 32 + (tid - 992)];
  __syncthreads();
  int grp = tid >> 5, lane = tid & 31;  // 32 groups
  float lh = 0.f;
  if (grp == 0) {  // eps at the level-4 root r
    int e = (r - 1) & 3;
    float ratio = srt[lane];
    float qv = spe[lane] / stb[lane];
    float num = 0.f, alh = 0.f;
#pragma unroll
    for (int j = 0; j < 32; j++) {
      float qq = __shfl(qv, j, 32);
      float te = ratio * sAT[e * 1024 + j * 32 + lane] * qq;
      num += te;
      alh += te * sLT[e * 1024 + j * 32 + lane];
    }
    float den = hsum32(num);
    float epsi = num / den;
    seps[lane] = epsi;
    lh += alh + epsi * W[W_LBT + labels[r] * 32 + lane];
  }
  __syncthreads();
  const int LOFF[5] = {0, 1, 5, 21, 85};
  const int GPOW[4] = {1, 4, 16, 64};
  for (int d = 1; d <= 3; d++) {
    int st = LOFF[d], cnt = LOFF[d + 1] - st;
    for (int base = 0; base < cnt; base += 32) {
      int idx = base + grp;
      if (idx < cnt) {
        int m = st + idx;
        int pa = (m - 1) >> 2, e = (m - 1) & 3;
        int g = GPOW[d] * r + m;
        float ratio = srt[m * 32 + lane];
        float qv = seps[pa * 32 + lane] / stb[m * 32 + lane];
        float num = 0.f, alh = 0.f;
#pragma unroll
        for (int j = 0; j < 32; j++) {
          float qq = __shfl(qv, j, 32);
          float te = ratio * sAT[e * 1024 + j * 32 + lane] * qq;
          num += te;
          alh += te * sLT[e * 1024 + j * 32 + lane];
        }
        float den = hsum32(num);
        float epsi = num / den;
        seps[m * 32 + lane] = epsi;
        lh += alh + epsi * W[W_LBT + labels[g] * 32 + lane];
      }
    }
    __syncthreads();
  }
#pragma unroll
  for (int m = 32; m >= 1; m >>= 1) lh += __shfl_xor(lh, m, 64);
  if ((tid & 63) == 0) sred[tid >> 6] = lh;
  __syncthreads();
  if (tid == 0) {
    float t = 0.f;
#pragma unroll
    for (int w = 0; w < 16; w++) t += sred[w];
    atomicAdd(out, t);
  }
}

extern "C" void kernel_launch(void* const* d_in, const int* in_sizes, int n_in,
                              void* d_out, int out_size, void* d_ws, size_t ws_size,
                              hipStream_t stream) {
  const float* A  = (const float*)d_in[0];
  const float* Bm = (const float*)d_in[1];
  const float* Pi = (const float*)d_in[2];
  const int* labels = (const int*)d_in[5];
  float* W = (float*)d_ws;
  float* out = (float*)d_out;

  k_pre<<<33, 256, 0, stream>>>(A, Bm, Pi, W, out);
  k_sub<<<256, 1024, 0, stream>>>(labels, W);
  k_mid<<<1, 1024, 0, stream>>>(labels, W, out);
  k_eps_sub<<<256, 1024, 0, stream>>>(labels, W, out);
}